// Round 3
// baseline (528.871 us; speedup 1.0000x reference)
//
#include <hip/hip_runtime.h>

#define B_   16
#define T_   512
#define V_   64
#define C1_  16
#define H_   64
#define TC_  256
#define NC_  10
#define INV_N (1.0f/524288.0f)   // 1/(B*T*V)
#define INV_T (1.0f/512.0f)

// ---------------------------------------------------------------- K0: adj_norm
// AnT[b][w][v] = dis[v]*A[v][w]*dis[w] (transposed: row w coalesced over v).
// Also zeroes the 2048-float stats partial area (16 blocks x 128 each).
__global__ __launch_bounds__(256) void k_adjnorm(const float* __restrict__ adj,
                                                 float* __restrict__ AnT,
                                                 float* __restrict__ statsP) {
  const int b = blockIdx.x;
  __shared__ float As[4096];
  __shared__ float dis[64];
  for (int idx = threadIdx.x; idx < 4096; idx += 256) As[idx] = adj[b * 4096 + idx];
  __syncthreads();
  if (threadIdx.x < 64) {
    const int v = threadIdx.x;
    float s = 0.f;
    // rotate column per lane: row stride is 64 floats (bank-invariant), so a
    // straight read puts all 64 lanes on one bank; (w+v)&63 fans the banks.
    #pragma unroll 8
    for (int w = 0; w < 64; ++w) s += As[v * 64 + ((w + v) & 63)];
    dis[v] = rsqrtf(s + 1e-6f);
  }
  __syncthreads();
  for (int idx = threadIdx.x; idx < 4096; idx += 256) {
    const int v = idx >> 6, w = idx & 63;
    AnT[b * 4096 + w * 64 + v] = dis[v] * As[v * 64 + w] * dis[w];
  }
  if (threadIdx.x < 128) statsP[b * 128 + threadIdx.x] = 0.f;
}

// ---------------------------------------------------------- K1: y = An@x (16ch)
// Each wave owns distinct t's (no redundancy). lane=v. x rows are wave-uniform
// (scalar loads); At column loads coalesced + L2-hot. Writes y[B,T,V,16] only.
__global__ __launch_bounds__(256) void k_gcn1(const float* __restrict__ x,
    const float* __restrict__ AnT, float* __restrict__ y) {
  const int b    = blockIdx.y;
  const int lane = threadIdx.x & 63;
  const int wq   = __builtin_amdgcn_readfirstlane(threadIdx.x >> 6);
  const float* __restrict__ At = AnT + b * 4096;
  for (int k = 0; k < 2; ++k) {
    const int t = blockIdx.x * 8 + wq * 2 + k;
    const float* __restrict__ xt = x + ((size_t)(b * T_ + t)) * V_ * C1_;
    float Y[16];
    #pragma unroll
    for (int i = 0; i < 16; ++i) Y[i] = 0.f;
    for (int w = 0; w < V_; ++w) {
      const float a = At[w * 64 + lane];
      const float* __restrict__ xr = xt + w * C1_;   // wave-uniform row
      #pragma unroll
      for (int c = 0; c < 16; ++c) Y[c] += a * xr[c];
    }
    float4* yo = (float4*)(y + (((size_t)(b * T_ + t)) * V_ + lane) * C1_);
    yo[0] = make_float4(Y[0], Y[1], Y[2], Y[3]);
    yo[1] = make_float4(Y[4], Y[5], Y[6], Y[7]);
    yo[2] = make_float4(Y[8], Y[9], Y[10], Y[11]);
    yo[3] = make_float4(Y[12], Y[13], Y[14], Y[15]);
  }
}

// ------------------------------------------- K1b: BN1 stats (z1 = y@W1 + b1)
// lane = output channel o; y rows wave-uniform (scalar loads). Per-lane
// sum/sumsq accumulators, block-level LDS reduce, 8 partial slots (low
// atomic contention).
__global__ __launch_bounds__(256) void k_stats1(const float* __restrict__ y,
    const float* __restrict__ w1, const float* __restrict__ b1,
    float* __restrict__ statsP) {
  const int lane = threadIdx.x & 63;
  const int wq   = __builtin_amdgcn_readfirstlane(threadIdx.x >> 6);
  float w1col[16];
  #pragma unroll
  for (int c = 0; c < 16; ++c) w1col[c] = w1[c * 64 + lane];
  const float bb = b1[lane];
  float ts0 = 0.f, ts1 = 0.f;
  const int row0 = blockIdx.x * 512 + wq * 128;
  for (int r = 0; r < 128; ++r) {
    const float* __restrict__ yr = y + (size_t)(row0 + r) * C1_;  // uniform
    float z = bb;
    #pragma unroll
    for (int c = 0; c < 16; ++c) z += yr[c] * w1col[c];
    ts0 += z; ts1 += z * z;
  }
  __shared__ float sred[4][128];
  sred[wq][lane]      = ts0;
  sred[wq][64 + lane] = ts1;
  __syncthreads();
  if (threadIdx.x < 128) {
    const float v = sred[0][threadIdx.x] + sred[1][threadIdx.x] +
                    sred[2][threadIdx.x] + sred[3][threadIdx.x];
    atomicAdd(&statsP[(blockIdx.x & 7) * 128 + threadIdx.x], v);
  }
}

// ---------------------------------------------------------------- K2: layer 2
// Prologue folds BN1 partials -> affine (b1 folded into shift). Per t: build
// x1 tile in LDS (y rows uniform s_load, W1 column per-lane), phase1
// P = An@x1 (uniform An rows), Pt transpose (stride 65), phase2 Z = P@W2
// (uniform W2 rows). Writes z2 + BN2 partial stats.
__global__ __launch_bounds__(256, 3) void k_gcn2(const float* __restrict__ y,
    const float* __restrict__ AnT, const float* __restrict__ w1,
    const float* __restrict__ b1, const float* __restrict__ g1,
    const float* __restrict__ be1, const float* __restrict__ w2,
    const float* __restrict__ b2, float* __restrict__ statsP,
    float* __restrict__ z2) {
  __shared__ float x1s[4096];
  __shared__ float Pt[64][65];
  __shared__ float aff[128];
  const int b    = blockIdx.y;
  const int t0   = blockIdx.x * 4;
  const int lane = threadIdx.x & 63;
  const int wq   = __builtin_amdgcn_readfirstlane(threadIdx.x >> 6);
  const int q0   = wq * 16;
  if (threadIdx.x < 64) {
    const int c = threadIdx.x;
    float s0 = 0.f, s1 = 0.f;
    #pragma unroll
    for (int s = 0; s < 8; ++s) { s0 += statsP[s * 128 + c]; s1 += statsP[s * 128 + 64 + c]; }
    const float mean = s0 * INV_N;
    const float var  = s1 * INV_N - mean * mean;
    const float sc   = g1[c] * rsqrtf(var + 1e-5f);
    aff[c]      = sc;
    aff[64 + c] = be1[c] - mean * sc + sc * b1[c];   // b1 folded in
  }
  __syncthreads();
  const float sc1 = aff[lane];
  const float shb = aff[64 + lane];
  float w1col[16];
  #pragma unroll
  for (int c = 0; c < 16; ++c) w1col[c] = w1[c * 64 + lane];
  const float* __restrict__ At = AnT + b * 4096;
  float ts0[16], ts1[16];
  #pragma unroll
  for (int i = 0; i < 16; ++i) { ts0[i] = 0.f; ts1[i] = 0.f; }

  for (int tt = 0; tt < 4; ++tt) {
    const int t = t0 + tt;
    const float* __restrict__ yt = y + ((size_t)(b * T_ + t)) * V_ * C1_;
    // build x1 tile: wave wq fills rows q0..q0+15, lane = column c
    #pragma unroll
    for (int k = 0; k < 16; ++k) {
      const int w = q0 + k;
      const float* __restrict__ yr = yt + w * C1_;   // wave-uniform
      float z = 0.f;
      #pragma unroll
      for (int c = 0; c < 16; ++c) z += yr[c] * w1col[c];
      x1s[w * 64 + lane] = fmaxf(z * sc1 + shb, 0.f);
    }
    __syncthreads();
    float P[16];
    #pragma unroll
    for (int i = 0; i < 16; ++i) P[i] = 0.f;
    for (int w = 0; w < 64; ++w) {
      const float xv = x1s[w * 64 + lane];             // 2-way alias: free
      const float* __restrict__ ar = At + w * 64 + q0; // uniform
      #pragma unroll
      for (int i = 0; i < 16; ++i) P[i] += ar[i] * xv;
    }
    #pragma unroll
    for (int i = 0; i < 16; ++i) Pt[lane][q0 + i] = P[i];
    __syncthreads();
    float Z[16];
    #pragma unroll
    for (int i = 0; i < 16; ++i) Z[i] = b2[q0 + i];
    for (int c = 0; c < 64; ++c) {
      const float p = Pt[c][lane];                     // stride 65: conflict-free
      const float* __restrict__ wr = w2 + c * 64 + q0; // uniform
      #pragma unroll
      for (int i = 0; i < 16; ++i) Z[i] += p * wr[i];
    }
    #pragma unroll
    for (int i = 0; i < 16; ++i) { const float v = Z[i]; ts0[i] += v; ts1[i] += v * v; }
    float4* zo = (float4*)(z2 + (((size_t)(b * T_ + t)) * V_ + lane) * H_ + q0);
    zo[0] = make_float4(Z[0], Z[1], Z[2], Z[3]);
    zo[1] = make_float4(Z[4], Z[5], Z[6], Z[7]);
    zo[2] = make_float4(Z[8], Z[9], Z[10], Z[11]);
    zo[3] = make_float4(Z[12], Z[13], Z[14], Z[15]);
    __syncthreads();   // x1s/Pt safe to overwrite next iteration
  }
  #pragma unroll
  for (int i = 0; i < 16; ++i) {
    float s0 = ts0[i], s1 = ts1[i];
    for (int off = 32; off > 0; off >>= 1) {
      s0 += __shfl_down(s0, off, 64);
      s1 += __shfl_down(s1, off, 64);
    }
    if (lane == 0) {
      atomicAdd(&statsP[(8 + (blockIdx.x & 7)) * 128 + q0 + i], s0);
      atomicAdd(&statsP[(8 + (blockIdx.x & 7)) * 128 + 64 + q0 + i], s1);
    }
  }
}

// ------------------------------------------------- K3: S/first/last reduction
// Folds both BN partial sets; recomputes z1 = y@W1 per row (y row uniform).
// xs = relu(aff1(z1)) + relu(aff2(z2)); per (b,v): S=sum_t, F=xs[0], L=xs[T-1].
__global__ __launch_bounds__(256) void k_sfl(const float* __restrict__ y,
    const float* __restrict__ z2, const float* __restrict__ statsP,
    const float* __restrict__ w1, const float* __restrict__ b1,
    const float* __restrict__ g1, const float* __restrict__ be1,
    const float* __restrict__ g2, const float* __restrict__ be2,
    float* __restrict__ S, float* __restrict__ F, float* __restrict__ L) {
  const int b = blockIdx.y, v = blockIdx.x;
  const int c  = threadIdx.x & 63;
  const int wq = __builtin_amdgcn_readfirstlane(threadIdx.x >> 6);
  float s0 = 0.f, s1 = 0.f, u0 = 0.f, u1 = 0.f;
  #pragma unroll
  for (int s = 0; s < 8; ++s) {
    s0 += statsP[s * 128 + c];       s1 += statsP[s * 128 + 64 + c];
    u0 += statsP[(8 + s) * 128 + c]; u1 += statsP[(8 + s) * 128 + 64 + c];
  }
  const float m1 = s0 * INV_N, va1 = s1 * INV_N - m1 * m1;
  const float sc1  = g1[c] * rsqrtf(va1 + 1e-5f);
  const float shb1 = be1[c] - m1 * sc1 + sc1 * b1[c];
  const float m2 = u0 * INV_N, va2 = u1 * INV_N - m2 * m2;
  const float sc2 = g2[c] * rsqrtf(va2 + 1e-5f);
  const float sh2 = be2[c] - m2 * sc2;
  float w1col[16];
  #pragma unroll
  for (int cc = 0; cc < 16; ++cc) w1col[cc] = w1[cc * 64 + c];

  float acc = 0.f, fv = 0.f, lv = 0.f;
  for (int t = wq; t < T_; t += 4) {
    const size_t row = ((size_t)(b * T_ + t)) * V_ + v;
    const float* __restrict__ yr = y + row * C1_;     // wave-uniform
    float z1v = 0.f;
    #pragma unroll
    for (int cc = 0; cc < 16; ++cc) z1v += yr[cc] * w1col[cc];
    const float x1 = fmaxf(z1v * sc1 + shb1, 0.f);
    const float x2 = fmaxf(z2[row * H_ + c] * sc2 + sh2, 0.f);
    const float xs = x1 + x2;
    acc += xs;
    if (t == 0) fv = xs;
    if (t == T_ - 1) lv = xs;
  }
  __shared__ float red[4][64];
  red[wq][c] = acc;
  __syncthreads();
  const int o = (b * V_ + v) * 64 + c;
  if (wq == 0) { S[o] = red[0][c] + red[1][c] + red[2][c] + red[3][c]; F[o] = fv; }
  if (wq == 3) L[o] = lv;
}

// ------------------------------ K4: folded conv+mean, twt read exactly once
// mean_t conv = (1/T)*[w0*(S-L) + w1*S + w2*(S-F)] (+tb in K5).
// Grid (co-group, K-chunk): block stages a0/a1/a2 for all 16 b over one
// 256-ci chunk (LDS stride 260: aligned + conflict-light), thread=(b,co)
// produces one partial.
__global__ __launch_bounds__(256) void k_pool(const float* __restrict__ S,
    const float* __restrict__ F, const float* __restrict__ L,
    const float* __restrict__ twt, float* __restrict__ mp) {
  const int cog = blockIdx.x;   // 0..15
  const int kc  = blockIdx.y;   // 0..15
  const int ci0 = kc * 256;
  __shared__ float a_s[3][16 * 260];
  for (int f4 = threadIdx.x; f4 < 3072; f4 += 256) {
    const int arr = f4 >> 10;
    const int rem = f4 & 1023;
    const int bb  = rem >> 6;
    const int ci4 = rem & 63;
    const float4 sv = *(const float4*)&S[bb * 4096 + ci0 + ci4 * 4];
    float4 o;
    if (arr == 0) {
      const float4 lv = *(const float4*)&L[bb * 4096 + ci0 + ci4 * 4];
      o = make_float4(sv.x - lv.x, sv.y - lv.y, sv.z - lv.z, sv.w - lv.w);
    } else if (arr == 1) {
      o = sv;
    } else {
      const float4 fvv = *(const float4*)&F[bb * 4096 + ci0 + ci4 * 4];
      o = make_float4(sv.x - fvv.x, sv.y - fvv.y, sv.z - fvv.z, sv.w - fvv.w);
    }
    *(float4*)&a_s[arr][bb * 260 + ci4 * 4] = o;
  }
  __syncthreads();
  const int bb   = threadIdx.x & 15;
  const int co   = threadIdx.x >> 4;
  const int co_g = cog * 16 + co;
  float acc = 0.f;
  for (int ci4 = 0; ci4 < 64; ++ci4) {
    const float4 a0 = *(const float4*)&a_s[0][bb * 260 + ci4 * 4];
    const float4 a1 = *(const float4*)&a_s[1][bb * 260 + ci4 * 4];
    const float4 a2 = *(const float4*)&a_s[2][bb * 260 + ci4 * 4];
    const float4* tp = (const float4*)(twt + ((size_t)co_g * 4096 + ci0 + ci4 * 4) * 3);
    const float4 f0 = tp[0], f1 = tp[1], f2 = tp[2];
    acc += f0.x * a0.x + f0.y * a1.x + f0.z * a2.x
         + f0.w * a0.y + f1.x * a1.y + f1.y * a2.y
         + f1.z * a0.z + f1.w * a1.z + f2.x * a2.z
         + f2.y * a0.w + f2.z * a1.w + f2.w * a2.w;
  }
  mp[kc * 4096 + bb * 256 + co_g] = acc;
}

// ------------------------------------------- K5: fold K-partials + FC head
__global__ __launch_bounds__(128) void k_head(const float* __restrict__ mp,
    const float* __restrict__ tb, const float* __restrict__ f1w,
    const float* __restrict__ f1b, const float* __restrict__ f2w,
    const float* __restrict__ f2b, float* __restrict__ out) {
  const int b = blockIdx.x;
  __shared__ float ms[256];
  __shared__ float hs[128];
  for (int co = threadIdx.x; co < 256; co += 128) {
    float s = 0.f;
    #pragma unroll
    for (int kc = 0; kc < 16; ++kc) s += mp[kc * 4096 + b * 256 + co];
    ms[co] = s * INV_T + tb[co];
  }
  __syncthreads();
  {
    const int j = threadIdx.x;
    float acc = f1b[j];
    #pragma unroll 8
    for (int k = 0; k < 256; ++k) acc += ms[k] * f1w[k * 128 + j];
    hs[j] = fmaxf(acc, 0.f);
  }
  __syncthreads();
  if (threadIdx.x < NC_) {
    const int n = threadIdx.x;
    float acc = f2b[n];
    #pragma unroll 8
    for (int j = 0; j < 128; ++j) acc += hs[j] * f2w[j * NC_ + n];
    out[b * NC_ + n] = acc;
  }
}

extern "C" void kernel_launch(void* const* d_in, const int* in_sizes, int n_in,
                              void* d_out, int out_size, void* d_ws, size_t ws_size,
                              hipStream_t stream) {
  const float* x   = (const float*)d_in[0];
  const float* adj = (const float*)d_in[1];
  const float* w1  = (const float*)d_in[2];
  const float* b1  = (const float*)d_in[3];
  const float* g1  = (const float*)d_in[4];
  const float* be1 = (const float*)d_in[5];
  const float* w2  = (const float*)d_in[6];
  const float* b2  = (const float*)d_in[7];
  const float* g2  = (const float*)d_in[8];
  const float* be2 = (const float*)d_in[9];
  const float* twt = (const float*)d_in[10];
  const float* tb  = (const float*)d_in[11];
  const float* f1w = (const float*)d_in[12];
  const float* f1b = (const float*)d_in[13];
  const float* f2w = (const float*)d_in[14];
  const float* f2b = (const float*)d_in[15];
  float* out = (float*)d_out;
  float* ws  = (float*)d_ws;

  // workspace layout (floats), total ~42.3M floats ~169 MB
  float* AnT    = ws;                    // 65536
  float* statsP = ws + 65536;            // 2048 (slots 0-7: BN1, 8-15: BN2)
  float* S      = ws + 67584;            // 65536
  float* F      = ws + 133120;           // 65536
  float* L      = ws + 198656;           // 65536
  float* mp     = ws + 264192;           // 65536
  float* y      = ws + 329728;           // 8388608
  float* z2     = y + (size_t)B_ * T_ * V_ * C1_;  // 33554432

  hipLaunchKernelGGL(k_adjnorm, dim3(B_), dim3(256), 0, stream, adj, AnT, statsP);
  hipLaunchKernelGGL(k_gcn1, dim3(T_ / 8, B_), dim3(256), 0, stream, x, AnT, y);
  hipLaunchKernelGGL(k_stats1, dim3(1024), dim3(256), 0, stream, y, w1, b1, statsP);
  hipLaunchKernelGGL(k_gcn2, dim3(T_ / 4, B_), dim3(256), 0, stream,
                     y, AnT, w1, b1, g1, be1, w2, b2, statsP, z2);
  hipLaunchKernelGGL(k_sfl, dim3(V_, B_), dim3(256), 0, stream,
                     y, z2, statsP, w1, b1, g1, be1, g2, be2, S, F, L);
  hipLaunchKernelGGL(k_pool, dim3(16, 16), dim3(256), 0, stream, S, F, L, twt, mp);
  hipLaunchKernelGGL(k_head, dim3(B_), dim3(128), 0, stream, mp, tb, f1w, f1b, f2w, f2b, out);
}